// Round 2
// baseline (1402.795 us; speedup 1.0000x reference)
//
#include <hip/hip_runtime.h>
#include <hip/hip_bf16.h>
#include <math.h>

// Problem constants (B=8,S=4096 -> N=32768 tokens)
#define NTOK   32768
#define HDIM   1024
#define FDIM   2048
#define F4DIM  512
#define NEXP   8
#define CAP    4096
#define EPSV   1e-6f

typedef __bf16 v8bf __attribute__((ext_vector_type(8)));
typedef float  v4f  __attribute__((ext_vector_type(4)));

// fp32 -> bf16 bits, round-to-nearest-even (finite inputs only)
__device__ __forceinline__ unsigned short f2b(float f) {
  unsigned int u = __float_as_uint(f);
  unsigned int r = (u + 0x7FFFu + ((u >> 16) & 1u)) >> 16;
  return (unsigned short)r;
}
__device__ __forceinline__ float b2f(unsigned short u) {
  return __uint_as_float(((unsigned int)u) << 16);
}

// async global->LDS, 16B per lane. LDS dest is WAVE-UNIFORM base + lane*16
// (m104/m108); global src is per-lane (m173) -> swizzle lives in the source addr.
__device__ __forceinline__ void gload16(unsigned short* lds, const unsigned short* g) {
  __builtin_amdgcn_global_load_lds(
      (const __attribute__((address_space(1))) unsigned int*)g,
      (__attribute__((address_space(3))) unsigned int*)lds, 16, 0, 0);
}

// ---------------- weight transpose + bf16 cast ----------------
// in: [z][rows][cols] fp32 row-major  ->  out: [z][cols][rows] bf16
__global__ __launch_bounds__(256) void transpose_cast(
    const float* __restrict__ in, unsigned short* __restrict__ out,
    int rows, int cols)
{
  __shared__ float tile[32][33];
  size_t zo = (size_t)blockIdx.z * rows * cols;
  in  += zo;
  out += zo;
  int c0 = blockIdx.x * 32, r0 = blockIdx.y * 32;
  int tx = threadIdx.x & 31, ty = threadIdx.x >> 5; // ty in 0..7
  for (int i = ty; i < 32; i += 8)
    tile[i][tx] = in[(size_t)(r0 + i) * cols + c0 + tx];
  __syncthreads();
  for (int i = ty; i < 32; i += 8)
    out[(size_t)(c0 + i) * rows + r0 + tx] = f2b(tile[tx][i]);
}

// ---------------- router: logits, softmax, top-2 ----------------
__global__ __launch_bounds__(256) void router_kernel(
    const float* __restrict__ x, const float* __restrict__ Wr,
    int* __restrict__ e1, int* __restrict__ e2,
    float* __restrict__ w1, float* __restrict__ w2)
{
  int wave = threadIdx.x >> 6, lane = threadIdx.x & 63;
  int t = blockIdx.x * 4 + wave;
  const float* xr = x + (size_t)t * HDIM;
  float acc[NEXP];
#pragma unroll
  for (int e = 0; e < NEXP; e++) acc[e] = 0.f;
  for (int j = 0; j < HDIM / 64; j++) {
    int h = lane + 64 * j;
    float v = xr[h];
    const float* wr = Wr + (size_t)h * NEXP;
#pragma unroll
    for (int e = 0; e < NEXP; e++) acc[e] += v * wr[e];
  }
#pragma unroll
  for (int e = 0; e < NEXP; e++) {
    float s = acc[e];
#pragma unroll
    for (int off = 32; off > 0; off >>= 1) s += __shfl_xor(s, off);
    acc[e] = s;
  }
  if (lane == 0) {
    float m = acc[0];
#pragma unroll
    for (int e = 1; e < NEXP; e++) m = fmaxf(m, acc[e]);
    float p[NEXP], sum = 0.f;
#pragma unroll
    for (int e = 0; e < NEXP; e++) { p[e] = expf(acc[e] - m); sum += p[e]; }
    float inv = 1.f / sum;
    // top-1: lowest index on ties (strict >)
    int b1 = 0; float v1 = p[0];
#pragma unroll
    for (int e = 1; e < NEXP; e++) if (p[e] > v1) { v1 = p[e]; b1 = e; }
    int b2 = -1; float v2 = -1.f;
#pragma unroll
    for (int e = 0; e < NEXP; e++) if (e != b1 && p[e] > v2) { v2 = p[e]; b2 = e; }
    e1[t] = b1; e2[t] = b2;
    w1[t] = v1 * inv; w2[t] = v2 * inv;
  }
}

// ---------------- capacity scan (exact cumsum order) ----------------
__global__ __launch_bounds__(256) void scan_count(
    const int* __restrict__ e1, const int* __restrict__ e2, int* __restrict__ chunkCnt)
{
  __shared__ int cnt[NEXP];
  if (threadIdx.x < NEXP) cnt[threadIdx.x] = 0;
  __syncthreads();
  int a = blockIdx.x * 256 + threadIdx.x;     // assignment id, 2N total
  int t = a >> 1;
  int e = (a & 1) ? e2[t] : e1[t];
  atomicAdd(&cnt[e], 1);
  __syncthreads();
  if (threadIdx.x < NEXP) chunkCnt[blockIdx.x * NEXP + threadIdx.x] = cnt[threadIdx.x];
}

__global__ __launch_bounds__(64) void scan_base(
    const int* __restrict__ chunkCnt, int* __restrict__ chunkBase)
{
  int e = threadIdx.x;
  if (e >= NEXP) return;
  int run = 0;
  for (int b = 0; b < 256; b++) {
    chunkBase[b * NEXP + e] = run;
    run += chunkCnt[b * NEXP + e];
  }
}

__global__ __launch_bounds__(64) void scan_pos(
    const int* __restrict__ e1, const int* __restrict__ e2,
    const int* __restrict__ chunkBase,
    int* __restrict__ posArr, int* __restrict__ slotTok)
{
  __shared__ int se[256];
  __shared__ int spos[256];
  int a0 = blockIdx.x * 256;
  for (int i = threadIdx.x; i < 256; i += 64) {
    int a = a0 + i;
    int t = a >> 1;
    se[i] = (a & 1) ? e2[t] : e1[t];
  }
  __syncthreads();
  if (threadIdx.x == 0) {
    int cnt[NEXP];
#pragma unroll
    for (int e = 0; e < NEXP; e++) cnt[e] = chunkBase[blockIdx.x * NEXP + e];
    for (int i = 0; i < 256; i++) spos[i] = cnt[se[i]]++;
  }
  __syncthreads();
  for (int i = threadIdx.x; i < 256; i += 64) {
    int a = a0 + i;
    int p = spos[i];
    posArr[a] = p;
    if (p < CAP) slotTok[se[i] * CAP + p] = a;   // store assignment id
  }
}

__global__ __launch_bounds__(256) void compute_ovf(
    const int* __restrict__ posArr, int* __restrict__ ovf)
{
  int t = blockIdx.x * 256 + threadIdx.x;
  ovf[t] = (posArr[2 * t] >= CAP || posArr[2 * t + 1] >= CAP) ? 1 : 0;
}

// ---------------- build RMSNorm'd bf16 A buffers ----------------
__global__ __launch_bounds__(256) void build_A(
    const float* __restrict__ x, const float* __restrict__ normw,
    const int* __restrict__ slotTok, unsigned short* __restrict__ A)
{
  int wave = threadIdx.x >> 6, lane = threadIdx.x & 63;
  int row = blockIdx.x * 4 + wave;            // [0, NEXP*CAP)
  int e = row >> 12;                          // /CAP
  ushort4* outp = (ushort4*)(A + (size_t)row * HDIM);
  int a = slotTok[row];
  if (a < 0) {
    ushort4 z; z.x = z.y = z.z = z.w = 0;
#pragma unroll
    for (int j = 0; j < 4; j++) outp[lane + 64 * j] = z;
    return;
  }
  int t = a >> 1;
  const float4* xr = (const float4*)(x + (size_t)t * HDIM);
  const float4* nw = (const float4*)(normw + (size_t)e * HDIM);
  float4 v[4];
  float ss = 0.f;
#pragma unroll
  for (int j = 0; j < 4; j++) {
    v[j] = xr[lane + 64 * j];
    ss += v[j].x * v[j].x + v[j].y * v[j].y + v[j].z * v[j].z + v[j].w * v[j].w;
  }
#pragma unroll
  for (int off = 32; off > 0; off >>= 1) ss += __shfl_xor(ss, off);
  float scale = rsqrtf(ss * (1.f / HDIM) + EPSV);
#pragma unroll
  for (int j = 0; j < 4; j++) {
    float4 w = nw[lane + 64 * j];
    ushort4 ov;
    ov.x = f2b(v[j].x * scale * w.x);
    ov.y = f2b(v[j].y * scale * w.y);
    ov.z = f2b(v[j].z * scale * w.z);
    ov.w = f2b(v[j].w * scale * w.w);
    outp[lane + 64 * j] = ov;
  }
}

__global__ __launch_bounds__(256) void build_fA(
    const float* __restrict__ x, const float* __restrict__ fnorm,
    unsigned short* __restrict__ A)
{
  int wave = threadIdx.x >> 6, lane = threadIdx.x & 63;
  int t = blockIdx.x * 4 + wave;
  ushort4* outp = (ushort4*)(A + (size_t)t * HDIM);
  const float4* xr = (const float4*)(x + (size_t)t * HDIM);
  const float4* nw = (const float4*)fnorm;
  float4 v[4];
  float ss = 0.f;
#pragma unroll
  for (int j = 0; j < 4; j++) {
    v[j] = xr[lane + 64 * j];
    ss += v[j].x * v[j].x + v[j].y * v[j].y + v[j].z * v[j].z + v[j].w * v[j].w;
  }
#pragma unroll
  for (int off = 32; off > 0; off >>= 1) ss += __shfl_xor(ss, off);
  float scale = rsqrtf(ss * (1.f / HDIM) + EPSV);
#pragma unroll
  for (int j = 0; j < 4; j++) {
    float4 w = nw[lane + 64 * j];
    ushort4 ov;
    ov.x = f2b(v[j].x * scale * w.x);
    ov.y = f2b(v[j].y * scale * w.y);
    ov.z = f2b(v[j].z * scale * w.z);
    ov.w = f2b(v[j].w * scale * w.w);
    outp[lane + 64 * j] = ov;
  }
}

// ---------------- 256x256 8-phase MFMA GEMM (T2+T3+T4+T5) ----------------
// A: [z][M][K] bf16 row-major. B: [z][N][K] bf16 (pre-transposed weight).
// MODE 0: Out = A@B^T (bf16)
// MODE 3: Out = gelu_exact(A@B^T) (bf16)              [gate pass]
// MODE 1: Out = b2f(Out) * (A@B^T)  in-place (bf16)   [up pass, Out holds gelu(G)]
// MODE 2: rows with ovf[row]: OutF[row] = Xres[row] + A@B^T (fp32), else skip
//
// Geometry: BM=BN=256, BK=64, 512 threads = 8 waves (2M x 4N), per-wave out
// 128x64 (acc[8][4] v4f). LDS = 2buf x 2half x 128rows x 64k x 2B x {A,B}
// = 128 KiB. Half-tiles are WAVE-ALIGNED: A-half h = rows of quadrant qm=h
// for both wm panels; B-half h = cols of quadrant qn=h for all wn panels.
// Phase (qm,qn) therefore reads exactly {A-half qm, B-half qn}.
//
// Per-iteration (2 K-tiles, phases ph1..ph8, quadrant order (0,0)(0,1)(1,1)(1,0)):
//   last reads per K-tile: A0->ph2, B1->ph3, A1->ph4, B0->ph4
//   staging slots:  ph1: T+1.{A1,B0}->other buf   (prev occupant last read prev ph4)
//                   ph3: T+2.A0 -> this buf       (this A0 last read ph2)
//                   ph4: T+2.B1 -> this buf       (this B1 last read ph3)
//   boundary s_waitcnt vmcnt(4) at ph4/ph8 trailing edge: newest 4 loads
//   (T+2.A0,B1) stay in flight; everything of T+1 (staged >=4 loads ago)
//   has landed. Never vmcnt(0) in the main loop (T4).
//
// Bank conflicts: rows are 128B (exact 32-bank wrap -> 16-way). Fix: both-sides
// 16B-chunk XOR swizzle chunk ^= (row&7) (rule #21): pre-swizzled global source
// at staging + swizzled ds_read addr. 16 lanes -> 8 chunks = 2-way = free (m136).
template<int MODE>
__global__ __launch_bounds__(512, 2) void gemm256(
    const unsigned short* __restrict__ A, size_t strideA,
    const unsigned short* __restrict__ B, size_t strideB,
    unsigned short* __restrict__ OutB, size_t strideO,
    float* __restrict__ OutF,
    const float* __restrict__ Xres,
    const int* __restrict__ ovf,
    int M, int N, int K)
{
  __shared__ __align__(16) unsigned short sA[2][2][128 * 64];
  __shared__ __align__(16) unsigned short sB[2][2][128 * 64];

  const int tid = threadIdx.x;
  const int wave = tid >> 6, lane = tid & 63;
  const int wm = wave >> 2, wn = wave & 3;        // 2 x 4 wave grid
  const int quad = lane >> 4, l16 = lane & 15;

  const int m0 = blockIdx.y * 256;
  const int n0 = blockIdx.x * 256;
  const int z = blockIdx.z;

  const unsigned short* Ab = A + (size_t)z * strideA + (size_t)m0 * K;
  const unsigned short* Bb = B + (size_t)z * strideB + (size_t)n0 * K;

  // ---- staging source offsets (per-lane, swizzled; loop-invariant) ----
  // gload g = wave*2+j writes LDS rows [g*8, g*8+8) of a half-tile; lane l
  // covers (row g*8+(l>>3), 16B-chunk l&7). Source chunk = (l&7)^(row&7).
  int offA[2][2], offB[2][2];
#pragma unroll
  for (int j = 0; j < 2; j++) {
    int g = wave * 2 + j;
    int ri = g * 8 + (lane >> 3);                 // LDS row in half-tile, 0..127
    int ch = (lane & 7) ^ (ri & 7);               // swizzled source chunk
#pragma unroll
    for (int h = 0; h < 2; h++) {
      int growA = (ri >> 6) * 128 + h * 64 + (ri & 63);   // wm-panel, qm=h rows
      int growB = (ri >> 5) * 64  + h * 32 + (ri & 31);   // wn-panel, qn=h cols
      offA[h][j] = growA * K + ch * 8;
      offB[h][j] = growB * K + ch * 8;
    }
  }

  auto stageA = [&](int buf, int h, int kb) {
#pragma unroll
    for (int j = 0; j < 2; j++)
      gload16(&sA[buf][h][(wave * 2 + j) * 512], Ab + offA[h][j] + kb);
  };
  auto stageB = [&](int buf, int h, int kb) {
#pragma unroll
    for (int j = 0; j < 2; j++)
      gload16(&sB[buf][h][(wave * 2 + j) * 512], Bb + offB[h][j] + kb);
  };

  v4f acc[8][4];
#pragma unroll
  for (int i = 0; i < 8; i++)
#pragma unroll
    for (int j = 0; j < 4; j++) acc[i][j] = (v4f){0.f, 0.f, 0.f, 0.f};

#define FRAG_MFMA(BUF, QM, QN)                                                  \
  do {                                                                          \
    v8bf af[4][2], bv[2][2];                                                    \
    const unsigned short* baseA = &sA[BUF][QM][0];                              \
    const unsigned short* baseB = &sB[BUF][QN][0];                              \
    _Pragma("unroll")                                                           \
    for (int mi = 0; mi < 4; mi++)                                              \
      _Pragma("unroll")                                                         \
      for (int ks = 0; ks < 2; ks++)                                            \
        af[mi][ks] = *(const v8bf*)(baseA + (wm * 64 + mi * 16 + l16) * 64 +    \
                                    (((ks * 4 + quad) ^ (l16 & 7)) * 8));       \
    _Pragma("unroll")                                                           \
    for (int nj = 0; nj < 2; nj++)                                              \
      _Pragma("unroll")                                                         \
      for (int ks = 0; ks < 2; ks++)                                            \
        bv[nj][ks] = *(const v8bf*)(baseB + (wn * 32 + nj * 16 + l16) * 64 +    \
                                    (((ks * 4 + quad) ^ (l16 & 7)) * 8));       \
    STAGE_STMT;                                                                 \
    __builtin_amdgcn_s_barrier();                                               \
    asm volatile("s_waitcnt lgkmcnt(0)" ::: "memory");                          \
    __builtin_amdgcn_sched_barrier(0);                                          \
    __builtin_amdgcn_s_setprio(1);                                              \
    _Pragma("unroll")                                                           \
    for (int mi = 0; mi < 4; mi++)                                              \
      _Pragma("unroll")                                                         \
      for (int nj = 0; nj < 2; nj++)                                            \
        _Pragma("unroll")                                                       \
        for (int ks = 0; ks < 2; ks++)                                          \
          acc[(QM) * 4 + mi][(QN) * 2 + nj] =                                   \
              __builtin_amdgcn_mfma_f32_16x16x32_bf16(                          \
                  af[mi][ks], bv[nj][ks], acc[(QM) * 4 + mi][(QN) * 2 + nj],    \
                  0, 0, 0);                                                     \
    __builtin_amdgcn_s_setprio(0);                                              \
    TAIL_STMT;                                                                  \
    __builtin_amdgcn_s_barrier();                                               \
    asm volatile("" ::: "memory");                                              \
  } while (0)

#define TAIL_NONE ((void)0)
#define TAIL_VM4                                                                \
  do {                                                                          \
    asm volatile("s_waitcnt vmcnt(4)" ::: "memory");                            \
    __builtin_amdgcn_sched_barrier(0);                                          \
  } while (0)

  // ---- prologue: T0 fully + T1.{A0,B1}; wait T0 (4 loads in flight) ----
  stageA(0, 0, 0); stageB(0, 0, 0); stageA(0, 1, 0); stageB(0, 1, 0);
  stageA(1, 0, 64); stageB(1, 1, 64);
  asm volatile("s_waitcnt vmcnt(4)" ::: "memory");
  __builtin_amdgcn_sched_barrier(0);
  __builtin_amdgcn_s_barrier();
  asm volatile("" ::: "memory");

  const int nt = K >> 6;                 // K-tiles (K % 128 == 0 for all uses)
  for (int t = 0; t < nt; t += 2) {
    const int kb1 = (t + 1) << 6;
    const int kb2 = (t + 2 < nt) ? (t + 2) << 6 : 0;   // clamped (garbage ok)
    const int kb3 = (t + 3 < nt) ? (t + 3) << 6 : 0;

    // K-tile t (buf0)
#define STAGE_STMT do { stageA(1, 1, kb1); stageB(1, 0, kb1); } while (0)
#define TAIL_STMT  TAIL_NONE
    FRAG_MFMA(0, 0, 0);                                 // ph1
#undef STAGE_STMT
#undef TAIL_STMT
#define STAGE_STMT ((void)0)
#define TAIL_STMT  TAIL_NONE
    FRAG_MFMA(0, 0, 1);                                 // ph2
#undef STAGE_STMT
#undef TAIL_STMT
#define STAGE_STMT stageA(0, 0, kb2)
#define TAIL_STMT  TAIL_NONE
    FRAG_MFMA(0, 1, 1);                                 // ph3
#undef STAGE_STMT
#undef TAIL_STMT
#define STAGE_STMT stageB(0, 1, kb2)
#define TAIL_STMT  TAIL_VM4
    FRAG_MFMA(0, 1, 0);                                 // ph4
#undef STAGE_STMT
#undef TAIL_STMT

    // K-tile t+1 (buf1)
#define STAGE_STMT do { stageA(0, 1, kb2); stageB(0, 0, kb2); } while (0)
#define TAIL_STMT  TAIL_NONE
    FRAG_MFMA(1, 0, 0);                                 // ph5
#undef STAGE_STMT
#undef TAIL_STMT
#define STAGE_STMT ((void)0)
#define TAIL_STMT  TAIL_NONE
    FRAG_MFMA(1, 0, 1);                                 // ph6
#undef STAGE_STMT
#undef TAIL_STMT
#define STAGE_STMT stageA(1, 0, kb3)
#define TAIL_STMT  TAIL_NONE
    FRAG_MFMA(1, 1, 1);                                 // ph7
#undef STAGE_STMT
#undef TAIL_STMT
#define STAGE_STMT stageB(1, 1, kb3)
#define TAIL_STMT  TAIL_VM4
    FRAG_MFMA(1, 1, 0);                                 // ph8
#undef STAGE_STMT
#undef TAIL_STMT
  }

  // ---- epilogue: C/D layout col=lane&15, row=quad*4+reg ----
  if constexpr (MODE == 0 || MODE == 1 || MODE == 3) {
    unsigned short* Ob = OutB + (size_t)z * strideO;
#pragma unroll
    for (int mi = 0; mi < 8; mi++) {
#pragma unroll
      for (int r = 0; r < 4; r++) {
        int row = m0 + wm * 128 + mi * 16 + quad * 4 + r;
#pragma unroll
        for (int nj = 0; nj < 4; nj++) {
          int col = n0 + wn * 64 + nj * 16 + l16;
          size_t idx = (size_t)row * N + col;
          float v = acc[mi][nj][r];
          if constexpr (MODE == 3) {
            v = 0.5f * v * (1.0f + erff(v * 0.70710678118654752f));
          } else if constexpr (MODE == 1) {
            v = b2f(Ob[idx]) * v;
          }
          Ob[idx] = f2b(v);
        }
      }
    }
  } else {  // MODE 2: overflow fallback rows, fp32 + residual
#pragma unroll
    for (int mi = 0; mi < 8; mi++) {
#pragma unroll
      for (int r = 0; r < 4; r++) {
        int row = m0 + wm * 128 + mi * 16 + quad * 4 + r;
        if (!ovf[row]) continue;
#pragma unroll
        for (int nj = 0; nj < 4; nj++) {
          int col = n0 + wn * 64 + nj * 16 + l16;
          OutF[(size_t)row * N + col] = Xres[(size_t)row * N + col] + acc[mi][nj][r];
        }
      }
    }
  }
#undef FRAG_MFMA
#undef TAIL_NONE
#undef TAIL_VM4
}

// ---------------- combine (non-overflow tokens) ----------------
__global__ __launch_bounds__(256) void combine_kernel(
    const float* __restrict__ x,
    const float* __restrict__ w1, const float* __restrict__ w2,
    const int* __restrict__ e1, const int* __restrict__ e2,
    const int* __restrict__ posArr, const int* __restrict__ ovf,
    const unsigned short* __restrict__ Y, float* __restrict__ out)
{
  int wave = threadIdx.x >> 6, lane = threadIdx.x & 63;
  int t = blockIdx.x * 4 + wave;
  if (ovf[t]) return;   // fallback GEMM wrote this row
  float a1 = w1[t], a2 = w2[t];
  int p1 = posArr[2 * t], p2 = posArr[2 * t + 1];
  const ushort4* y1 = (const ushort4*)(Y + ((size_t)e1[t] * CAP + p1) * HDIM);
  const ushort4* y2 = (const ushort4*)(Y + ((size_t)e2[t] * CAP + p2) * HDIM);
  const float4* xr = (const float4*)(x + (size_t)t * HDIM);
  float4* o = (float4*)(out + (size_t)t * HDIM);
  float base = 1.f + a1 + a2;
#pragma unroll
  for (int j = 0; j < 4; j++) {
    int i = lane + 64 * j;
    float4 xv = xr[i];
    ushort4 u1 = y1[i], u2 = y2[i];
    float4 r;
    r.x = base * xv.x + a1 * b2f(u1.x) + a2 * b2f(u2.x);
    r.y = base * xv.y + a1 * b2f(u1.y) + a2 * b2f(u2.y);
    r.z = base * xv.z + a1 * b2f(u1.z) + a2 * b2f(u2.z);
    r.w = base * xv.w + a1 * b2f(u1.w) + a2 * b2f(u2.w);
    o[i] = r;
  }
}

// ---------------- launch ----------------
extern "C" void kernel_launch(void* const* d_in, const int* in_sizes, int n_in,
                              void* d_out, int out_size, void* d_ws, size_t ws_size,
                              hipStream_t stream) {
  const float* x     = (const float*)d_in[0];
  const float* Wr    = (const float*)d_in[1];
  const float* normw = (const float*)d_in[2];
  const float* Wg    = (const float*)d_in[3];
  const float* Wu    = (const float*)d_in[4];
  const float* Wd    = (const float*)d_in[5];
  const float* fnorm = (const float*)d_in[6];
  const float* fWg   = (const float*)d_in[7];
  const float* fWu   = (const float*)d_in[8];
  const float* fWd   = (const float*)d_in[9];
  float* out = (float*)d_out;

  // workspace layout (~372 MiB); fA aliases A, fP aliases P; G/fG live in P/fP
  char* p = (char*)d_ws;
  auto alloc = [&](size_t bytes) {
    char* r = p; p += (bytes + 255) & ~(size_t)255; return r;
  };
  unsigned short* WgT  = (unsigned short*)alloc((size_t)NEXP * FDIM * HDIM * 2);
  unsigned short* WuT  = (unsigned short*)alloc((size_t)NEXP * FDIM * HDIM * 2);
  unsigned short* WdT  = (unsigned short*)alloc((size_t)NEXP * HDIM * FDIM * 2);
  unsigned short* fWgT = (unsigned short*)alloc((size_t)F4DIM * HDIM * 2);
  unsigned short* fWuT = (unsigned short*)alloc((size_t)F4DIM * HDIM * 2);
  unsigned short* fWdT = (unsigned short*)alloc((size_t)HDIM * F4DIM * 2);
  unsigned short* Abuf = (unsigned short*)alloc((size_t)NEXP * CAP * HDIM * 2);   // later fA
  unsigned short* Pbuf = (unsigned short*)alloc((size_t)NEXP * CAP * FDIM * 2);   // G then P; later fG/fP
  unsigned short* Ybuf = (unsigned short*)alloc((size_t)NEXP * CAP * HDIM * 2);
  int*   e1      = (int*)alloc((size_t)NTOK * 4);
  int*   e2      = (int*)alloc((size_t)NTOK * 4);
  float* w1      = (float*)alloc((size_t)NTOK * 4);
  float* w2      = (float*)alloc((size_t)NTOK * 4);
  int*   posArr  = (int*)alloc((size_t)2 * NTOK * 4);
  int*   ovf     = (int*)alloc((size_t)NTOK * 4);
  int*   chunkCnt  = (int*)alloc(256 * NEXP * 4);
  int*   chunkBase = (int*)alloc(256 * NEXP * 4);
  int*   slotTok   = (int*)alloc((size_t)NEXP * CAP * 4);
  unsigned short* fAbuf = Abuf;   // alias: A dead after main-path GEMMs
  unsigned short* fPbuf = Pbuf;   // alias: P dead after GEMM2

  hipMemsetAsync(slotTok, 0xFF, (size_t)NEXP * CAP * 4, stream);  // -1

  // weight transpose+cast to bf16 [N][K]
  transpose_cast<<<dim3(FDIM / 32, HDIM / 32, NEXP), 256, 0, stream>>>(Wg, WgT, HDIM, FDIM);
  transpose_cast<<<dim3(FDIM / 32, HDIM / 32, NEXP), 256, 0, stream>>>(Wu, WuT, HDIM, FDIM);
  transpose_cast<<<dim3(HDIM / 32, FDIM / 32, NEXP), 256, 0, stream>>>(Wd, WdT, FDIM, HDIM);
  transpose_cast<<<dim3(F4DIM / 32, HDIM / 32, 1), 256, 0, stream>>>(fWg, fWgT, HDIM, F4DIM);
  transpose_cast<<<dim3(F4DIM / 32, HDIM / 32, 1), 256, 0, stream>>>(fWu, fWuT, HDIM, F4DIM);
  transpose_cast<<<dim3(HDIM / 32, F4DIM / 32, 1), 256, 0, stream>>>(fWd, fWdT, F4DIM, HDIM);

  router_kernel<<<NTOK / 4, 256, 0, stream>>>(x, Wr, e1, e2, w1, w2);
  scan_count<<<256, 256, 0, stream>>>(e1, e2, chunkCnt);
  scan_base<<<1, 64, 0, stream>>>(chunkCnt, chunkBase);
  scan_pos<<<256, 64, 0, stream>>>(e1, e2, chunkBase, posArr, slotTok);
  compute_ovf<<<NTOK / 256, 256, 0, stream>>>(posArr, ovf);

  build_A<<<NEXP * CAP / 4, 256, 0, stream>>>(x, normw, slotTok, Abuf);

  // expert GLU, split (3rd operand doesn't fit 128KiB LDS):
  //   Pbuf = gelu(A@Wg);  Pbuf *= A@Wu  (in-place, element-wise by same thread)
  gemm256<3><<<dim3(FDIM / 256, CAP / 256, NEXP), 512, 0, stream>>>(
      Abuf, (size_t)CAP * HDIM, WgT, (size_t)FDIM * HDIM,
      Pbuf, (size_t)CAP * FDIM, nullptr, nullptr, nullptr, CAP, FDIM, HDIM);
  gemm256<1><<<dim3(FDIM / 256, CAP / 256, NEXP), 512, 0, stream>>>(
      Abuf, (size_t)CAP * HDIM, WuT, (size_t)FDIM * HDIM,
      Pbuf, (size_t)CAP * FDIM, nullptr, nullptr, nullptr, CAP, FDIM, HDIM);
  // Y = P@Wd
  gemm256<0><<<dim3(HDIM / 256, CAP / 256, NEXP), 512, 0, stream>>>(
      Pbuf, (size_t)CAP * FDIM, WdT, (size_t)HDIM * FDIM,
      Ybuf, (size_t)CAP * HDIM, nullptr, nullptr, nullptr, CAP, HDIM, FDIM);

  // fallback path (A region and P region reused)
  build_fA<<<NTOK / 4, 256, 0, stream>>>(x, fnorm, fAbuf);
  gemm256<3><<<dim3(F4DIM / 256, NTOK / 256, 1), 512, 0, stream>>>(
      fAbuf, 0, fWgT, 0,
      fPbuf, 0, nullptr, nullptr, nullptr, NTOK, F4DIM, HDIM);
  gemm256<1><<<dim3(F4DIM / 256, NTOK / 256, 1), 512, 0, stream>>>(
      fAbuf, 0, fWuT, 0,
      fPbuf, 0, nullptr, nullptr, nullptr, NTOK, F4DIM, HDIM);
  gemm256<2><<<dim3(HDIM / 256, NTOK / 256, 1), 512, 0, stream>>>(
      fPbuf, 0, fWdT, 0,
      nullptr, 0, out, x, ovf, NTOK, HDIM, F4DIM);

  combine_kernel<<<NTOK / 4, 256, 0, stream>>>(x, w1, w2, e1, e2, posArr, ovf, Ybuf, out);
}